// Round 10
// baseline (472.772 us; speedup 1.0000x reference)
//
#include <hip/hip_runtime.h>
#include <cmath>

// Problem constants (fixed by reference file)
#define B_     8
#define NH_    32
#define HD_    128
#define HID_   4096
#define MAXS_  4096
#define NPAIR_ (B_ * NH_)          // 256 (b,h) pairs
#define NSPLIT_ 4                  // key-splits per pair
#define PSTR_  132                 // partial stride: m, l, pad, pad, acc[128]
#define NEG_BIG_ (-1e30f)

typedef float f4_ __attribute__((ext_vector_type(4)));

__device__ __forceinline__ f4_ ntload4(const float* p) {
  return __builtin_nontemporal_load((const f4_*)p);
}
__device__ __forceinline__ f4_ ld4(const float* p) {
  return *(const f4_*)p;
}
__device__ __forceinline__ float dot4(f4_ a, f4_ b) {
  f4_ m = a * b;
  return m.x + m.y + m.z + m.w;
}

// Deep-ILP register-double-buffered GEMV.
// out[b][row] = sum_j W[row][j] * x[b][j], W in {W0,W1,W2} by bid/nb_per_mat.
// 8 rows/block, 2 rows/wave; K=4096 as 4 groups of 4 slices (256 floats).
// While computing group g (64 dot4 = 256 FMA per thread-pair of rows), the
// NEXT group's 8 weight f4s are in flight in registers (8 KB/wave, no LDS,
// no barriers) -> in-flight bytes/CU >> Little's-law need, unlike the
// compiler's own ~2-load pipeline (VGPR_Count=40 in round-8 probe).
// Weights NORMAL loads (L3-resident across replays; nt KV can't evict).
// Round-9 lesson: NO __syncthreads in the stream loop (vmcnt(0) drain).
__global__ __launch_bounds__(256) void gemv_deep(
    const float* __restrict__ W0, const float* __restrict__ W1,
    const float* __restrict__ W2, const float* __restrict__ x,
    float* __restrict__ out, int nb_per_mat)
{
  const int bid = blockIdx.x;
  const int m   = bid / nb_per_mat;       // matrix index (0..2)
  const int rb  = (bid % nb_per_mat) * 8; // first of 8 rows
  const float* __restrict__ W = (m == 0) ? W0 : ((m == 1) ? W1 : W2);
  float* o = out + m * (B_ * HID_);

  const int wib  = threadIdx.x >> 6;
  const int lane = threadIdx.x & 63;
  const int r0   = rb + wib * 2;          // 2 rows per wave

  float acc[2][8];
#pragma unroll
  for (int r = 0; r < 2; ++r)
#pragma unroll
    for (int b = 0; b < 8; ++b) acc[r][b] = 0.f;

  const float* Wp = W + (size_t)r0 * HID_ + lane * 4;

  f4_ wa[2][4], wb[2][4];                 // two 4-slice register buffers

#define LOADG_(BUF, g)                                                       \
  {                                                                          \
    _Pragma("unroll")                                                        \
    for (int r = 0; r < 2; ++r)                                              \
      _Pragma("unroll")                                                      \
      for (int k = 0; k < 4; ++k)                                            \
        BUF[r][k] = ld4(Wp + (size_t)r * HID_ + ((g) * 4 + k) * 256);        \
  }

#define COMPG_(BUF, g)                                                       \
  {                                                                          \
    _Pragma("unroll")                                                        \
    for (int k = 0; k < 4; ++k) {                                            \
      const int j = ((g) * 4 + k) * 256;                                     \
      _Pragma("unroll")                                                      \
      for (int b = 0; b < 8; ++b) {                                          \
        f4_ xb = ld4(x + b * HID_ + j + lane * 4);                           \
        acc[0][b] += dot4(BUF[0][k], xb);                                    \
        acc[1][b] += dot4(BUF[1][k], xb);                                    \
      }                                                                      \
    }                                                                        \
  }

  LOADG_(wa, 0);
  LOADG_(wb, 1); COMPG_(wa, 0);           // issue g+1, compute g
  LOADG_(wa, 2); COMPG_(wb, 1);
  LOADG_(wb, 3); COMPG_(wa, 2);
  COMPG_(wb, 3);
#undef LOADG_
#undef COMPG_

  // butterfly reduce each partial across the 64-lane wave
#pragma unroll
  for (int r = 0; r < 2; ++r)
#pragma unroll
    for (int b = 0; b < 8; ++b) {
      float v = acc[r][b];
#pragma unroll
      for (int off = 32; off; off >>= 1) v += __shfl_xor(v, off);
      acc[r][b] = v;
    }

  if (lane == 0) {
#pragma unroll
    for (int r = 0; r < 2; ++r)
#pragma unroll
      for (int b = 0; b < 8; ++b)
        o[(size_t)b * HID_ + r0 + r] = acc[r][b];
  }
}

// Flash-decoding partials: 4 blocks (256 thr = 4 waves) per (b,h) pair.
// K/V rows nt (stream-once; must not evict L3-resident weights).
__global__ __launch_bounds__(256, 4) void attn_partial(
    const float* __restrict__ qkv, const float* __restrict__ ck,
    const float* __restrict__ cv, const int* __restrict__ ppos,
    float* __restrict__ part)
{
  __shared__ float sm[4], sl[4];
  __shared__ float sacc[4][HD_];

  const int pos  = *ppos;
  const int bid  = blockIdx.x;
  const int pair = bid >> 2;
  const int s    = bid & (NSPLIT_ - 1);
  const int b    = pair >> 5;
  const int h    = pair & (NH_ - 1);
  const int w    = threadIdx.x >> 6;
  const int lane = threadIdx.x & 63;
  const int half = lane >> 5, l32 = lane & 31;
  const int k0   = s * 512 + w * 128;

  float m = NEG_BIG_, l = 0.f;
  f4_ acc = (f4_)0.f;

  if (k0 <= pos) {
    const float scale = 0.08838834764831845f;   // 1/sqrt(128)
    f4_ q4 = ld4(qkv + b * HID_ + h * HD_ + l32 * 4) * scale;
    const float* kfresh = qkv + B_ * HID_     + b * HID_ + h * HD_;
    const float* vfresh = qkv + 2 * B_ * HID_ + b * HID_ + h * HD_;
    const float* ckh = ck + ((size_t)(b * NH_ + h)) * MAXS_ * HD_;
    const float* cvh = cv + ((size_t)(b * NH_ + h)) * MAXS_ * HD_;

    for (int c = 0; c < 8; ++c) {
      const int kbase = k0 + c * 16;
      f4_ k4[8], v4[8];
#pragma unroll
      for (int j = 0; j < 8; ++j) {
        const int ki = kbase + 2 * j + half;
        const float* kp = (ki == pos) ? kfresh : (ckh + (size_t)ki * HD_);
        const float* vp = (ki == pos) ? vfresh : (cvh + (size_t)ki * HD_);
        k4[j] = ntload4(kp + l32 * 4);
        v4[j] = ntload4(vp + l32 * 4);
      }

      float sc[8];
#pragma unroll
      for (int j = 0; j < 8; ++j) sc[j] = dot4(q4, k4[j]);

#pragma unroll
      for (int off = 16; off >= 1; off >>= 1)
#pragma unroll
        for (int j = 0; j < 8; ++j) sc[j] += __shfl_xor(sc[j], off);

#pragma unroll
      for (int j = 0; j < 8; ++j) {
        const int ki = kbase + 2 * j + half;
        if (ki > pos) sc[j] = -INFINITY;
      }

      const float cm = fmaxf(fmaxf(fmaxf(sc[0], sc[1]), fmaxf(sc[2], sc[3])),
                             fmaxf(fmaxf(sc[4], sc[5]), fmaxf(sc[6], sc[7])));
      const float mn   = fmaxf(m, cm);
      const float corr = __expf(m - mn);
      float p[8], ps = 0.f;
#pragma unroll
      for (int j = 0; j < 8; ++j) { p[j] = __expf(sc[j] - mn); ps += p[j]; }
      l = l * corr + ps;
      acc *= corr;
#pragma unroll
      for (int j = 0; j < 8; ++j) acc += p[j] * v4[j];
      m = mn;
    }
  }

  const float mo = __shfl_xor(m, 32);
  const float lo = __shfl_xor(l, 32);
  f4_ ao;
  ao.x = __shfl_xor(acc.x, 32); ao.y = __shfl_xor(acc.y, 32);
  ao.z = __shfl_xor(acc.z, 32); ao.w = __shfl_xor(acc.w, 32);
  const float mm = fmaxf(m, mo);
  const float w0 = __expf(m - mm), w1 = __expf(mo - mm);
  const float lm = l * w0 + lo * w1;
  f4_ am = acc * w0 + ao * w1;

  if (half == 0) {
    *(f4_*)&sacc[w][l32 * 4] = am;
    if (l32 == 0) { sm[w] = mm; sl[w] = lm; }
  }
  __syncthreads();

  if (threadIdx.x < 32) {
    const int t = threadIdx.x;
    float mg = NEG_BIG_;
#pragma unroll
    for (int u = 0; u < 4; ++u)
      if (sl[u] > 0.f) mg = fmaxf(mg, sm[u]);
    float ls = 0.f;
    f4_ o = (f4_)0.f;
#pragma unroll
    for (int u = 0; u < 4; ++u)
      if (sl[u] > 0.f) {
        const float wu = __expf(sm[u] - mg);
        ls += sl[u] * wu;
        o  += wu * ld4(&sacc[u][t * 4]);
      }
    float* pb = part + (size_t)bid * PSTR_;
    *(f4_*)(pb + 4 + t * 4) = o;
    if (t == 0) { pb[0] = (ls > 0.f) ? mg : NEG_BIG_; pb[1] = ls; }
  }
}

// Merge the 4 split partials per (b,h) into attn output [b][h*128+d].
__global__ __launch_bounds__(128) void attn_combine(
    const float* __restrict__ part, float* __restrict__ attnout)
{
  const int pair = blockIdx.x;
  const int d    = threadIdx.x;
  const float* pb = part + (size_t)pair * NSPLIT_ * PSTR_;

  float mg = NEG_BIG_;
#pragma unroll
  for (int u = 0; u < NSPLIT_; ++u) {
    const float lu = pb[u * PSTR_ + 1];
    if (lu > 0.f) mg = fmaxf(mg, pb[u * PSTR_]);
  }
  float ls = 0.f, o = 0.f;
#pragma unroll
  for (int u = 0; u < NSPLIT_; ++u) {
    const float lu = pb[u * PSTR_ + 1];
    if (lu > 0.f) {
      const float wu = __expf(pb[u * PSTR_] - mg);
      ls += lu * wu;
      o  += wu * pb[u * PSTR_ + 4 + d];
    }
  }
  attnout[pair * HD_ + d] = o / ls;
}

extern "C" void kernel_launch(void* const* d_in, const int* in_sizes, int n_in,
                              void* d_out, int out_size, void* d_ws, size_t ws_size,
                              hipStream_t stream) {
  const float* x  = (const float*)d_in[0];
  const float* ck = (const float*)d_in[1];
  const float* cv = (const float*)d_in[2];
  const float* wq = (const float*)d_in[3];
  const float* wk = (const float*)d_in[4];
  const float* wv = (const float*)d_in[5];
  const float* wo = (const float*)d_in[6];
  const int* pos  = (const int*)d_in[7];
  float* out = (float*)d_out;
  float* ws  = (float*)d_ws;

  float* qkv     = ws;                                   // 3*8*4096 floats
  float* part    = ws + 3 * B_ * HID_;                   // 1024 * 132 floats
  float* attnout = part + NPAIR_ * NSPLIT_ * PSTR_;      // 8*4096 floats

  gemv_deep<<<3 * 512, 256, 0, stream>>>(wq, wk, wv, x, qkv, 512);
  attn_partial<<<NPAIR_ * NSPLIT_, 256, 0, stream>>>(qkv, ck, cv, pos, part);
  attn_combine<<<NPAIR_, 128, 0, stream>>>(part, attnout);
  gemv_deep<<<512, 256, 0, stream>>>(wo, wo, wo, attnout, out, 512);
}

// Round 11
// 178.529 us; speedup vs baseline: 2.6482x; 2.6482x over previous
//
#include <hip/hip_runtime.h>
#include <cmath>

// Problem constants (fixed by reference file)
#define B_     8
#define NH_    32
#define HD_    128
#define HID_   4096
#define MAXS_  4096
#define NPAIR_ (B_ * NH_)          // 256 (b,h) pairs
#define NSPLIT_ 4                  // key-splits per pair
#define PSTR_  132                 // partial stride: m, l, pad, pad, acc[128]
#define NEG_BIG_ (-1e30f)

typedef float f4_ __attribute__((ext_vector_type(4)));

__device__ __forceinline__ f4_ ntload4(const float* p) {
  return __builtin_nontemporal_load((const f4_*)p);
}
__device__ __forceinline__ f4_ ld4(const float* p) {
  return *(const f4_*)p;
}
__device__ __forceinline__ float dot4(f4_ a, f4_ b) {
  f4_ m = a * b;
  return m.x + m.y + m.z + m.w;
}

// TA-efficient GEMV: 1 wave (64 thr) per block, 8 rows/block, all 8 batches.
// Per K-slice (256 floats): 8 w-loads + 8 x-loads -> weights are 50% of
// VMEM-port bytes (vs 20% at 2 rows/wave; round-8 probe showed the gemv is
// L1/TA-instruction-throughput-bound at ~53 B/cy/CU, so weight fraction is
// the lever). Register-double-buffered weights (wa/wb, static indices);
// issue order per phase: x first, THEN next-slice w prefetch — vmcnt is
// in-order, so x-waits must not be able to drain the w prefetch (round-10
// lesson). #pragma unroll 1 keeps the 2-phase loop structure (round-10's
// full unroll -> 256 VGPR pathology).
// Weights NORMAL loads (L3-resident across replays; nt KV can't evict).
__global__ __launch_bounds__(64) void gemv8(
    const float* __restrict__ W0, const float* __restrict__ W1,
    const float* __restrict__ W2, const float* __restrict__ x,
    float* __restrict__ out, int nb_per_mat)
{
  const int bid = blockIdx.x;
  const int m   = bid / nb_per_mat;       // matrix index (0..2)
  const int r0  = (bid % nb_per_mat) * 8; // first of 8 rows
  const float* __restrict__ W = (m == 0) ? W0 : ((m == 1) ? W1 : W2);
  float* o = out + m * (B_ * HID_);

  const int lane = threadIdx.x;           // 0..63

  float acc[8][8];
#pragma unroll
  for (int r = 0; r < 8; ++r)
#pragma unroll
    for (int b = 0; b < 8; ++b) acc[r][b] = 0.f;

  const float* Wp = W + (size_t)r0 * HID_ + lane * 4;
  const float* xp = x + lane * 4;

  f4_ wa[8], wb[8];
  // prologue: slice 0 weights into wa
#pragma unroll
  for (int r = 0; r < 8; ++r) wa[r] = ld4(Wp + (size_t)r * HID_);

#pragma unroll 1
  for (int u = 0; u < 16; u += 2) {
    // ---- phase A: compute slice u from wa; prefetch u+1 into wb ----
    {
      const int j = u * 256;
      f4_ xv[8];
#pragma unroll
      for (int b = 0; b < 8; ++b) xv[b] = ld4(xp + b * HID_ + j);
#pragma unroll
      for (int r = 0; r < 8; ++r)
        wb[r] = ld4(Wp + (size_t)r * HID_ + j + 256);
#pragma unroll
      for (int r = 0; r < 8; ++r)
#pragma unroll
        for (int b = 0; b < 8; ++b) acc[r][b] += dot4(wa[r], xv[b]);
    }
    // ---- phase B: compute slice u+1 from wb; prefetch u+2 into wa ----
    {
      const int j = (u + 1) * 256;
      f4_ xv[8];
#pragma unroll
      for (int b = 0; b < 8; ++b) xv[b] = ld4(xp + b * HID_ + j);
      if (u + 2 < 16) {
#pragma unroll
        for (int r = 0; r < 8; ++r)
          wa[r] = ld4(Wp + (size_t)r * HID_ + j + 256);
      }
#pragma unroll
      for (int r = 0; r < 8; ++r)
#pragma unroll
        for (int b = 0; b < 8; ++b) acc[r][b] += dot4(wb[r], xv[b]);
    }
  }

  // butterfly reduce each of the 64 partials across the wave
#pragma unroll
  for (int r = 0; r < 8; ++r)
#pragma unroll
    for (int b = 0; b < 8; ++b) {
      float v = acc[r][b];
#pragma unroll
      for (int off = 32; off; off >>= 1) v += __shfl_xor(v, off);
      acc[r][b] = v;
    }

  if (lane == 0) {
#pragma unroll
    for (int r = 0; r < 8; ++r)
#pragma unroll
      for (int b = 0; b < 8; ++b)
        o[(size_t)b * HID_ + r0 + r] = acc[r][b];
  }
}

// Flash-decoding partials: 4 blocks (256 thr = 4 waves) per (b,h) pair.
// K/V rows nt (stream-once; must not evict L3-resident weights).
__global__ __launch_bounds__(256, 4) void attn_partial(
    const float* __restrict__ qkv, const float* __restrict__ ck,
    const float* __restrict__ cv, const int* __restrict__ ppos,
    float* __restrict__ part)
{
  __shared__ float sm[4], sl[4];
  __shared__ float sacc[4][HD_];

  const int pos  = *ppos;
  const int bid  = blockIdx.x;
  const int pair = bid >> 2;
  const int s    = bid & (NSPLIT_ - 1);
  const int b    = pair >> 5;
  const int h    = pair & (NH_ - 1);
  const int w    = threadIdx.x >> 6;
  const int lane = threadIdx.x & 63;
  const int half = lane >> 5, l32 = lane & 31;
  const int k0   = s * 512 + w * 128;

  float m = NEG_BIG_, l = 0.f;
  f4_ acc = (f4_)0.f;

  if (k0 <= pos) {
    const float scale = 0.08838834764831845f;   // 1/sqrt(128)
    f4_ q4 = ld4(qkv + b * HID_ + h * HD_ + l32 * 4) * scale;
    const float* kfresh = qkv + B_ * HID_     + b * HID_ + h * HD_;
    const float* vfresh = qkv + 2 * B_ * HID_ + b * HID_ + h * HD_;
    const float* ckh = ck + ((size_t)(b * NH_ + h)) * MAXS_ * HD_;
    const float* cvh = cv + ((size_t)(b * NH_ + h)) * MAXS_ * HD_;

    for (int c = 0; c < 8; ++c) {
      const int kbase = k0 + c * 16;
      f4_ k4[8], v4[8];
#pragma unroll
      for (int j = 0; j < 8; ++j) {
        const int ki = kbase + 2 * j + half;
        const float* kp = (ki == pos) ? kfresh : (ckh + (size_t)ki * HD_);
        const float* vp = (ki == pos) ? vfresh : (cvh + (size_t)ki * HD_);
        k4[j] = ntload4(kp + l32 * 4);
        v4[j] = ntload4(vp + l32 * 4);
      }

      float sc[8];
#pragma unroll
      for (int j = 0; j < 8; ++j) sc[j] = dot4(q4, k4[j]);

#pragma unroll
      for (int off = 16; off >= 1; off >>= 1)
#pragma unroll
        for (int j = 0; j < 8; ++j) sc[j] += __shfl_xor(sc[j], off);

#pragma unroll
      for (int j = 0; j < 8; ++j) {
        const int ki = kbase + 2 * j + half;
        if (ki > pos) sc[j] = -INFINITY;
      }

      const float cm = fmaxf(fmaxf(fmaxf(sc[0], sc[1]), fmaxf(sc[2], sc[3])),
                             fmaxf(fmaxf(sc[4], sc[5]), fmaxf(sc[6], sc[7])));
      const float mn   = fmaxf(m, cm);
      const float corr = __expf(m - mn);
      float p[8], ps = 0.f;
#pragma unroll
      for (int j = 0; j < 8; ++j) { p[j] = __expf(sc[j] - mn); ps += p[j]; }
      l = l * corr + ps;
      acc *= corr;
#pragma unroll
      for (int j = 0; j < 8; ++j) acc += p[j] * v4[j];
      m = mn;
    }
  }

  const float mo = __shfl_xor(m, 32);
  const float lo = __shfl_xor(l, 32);
  f4_ ao;
  ao.x = __shfl_xor(acc.x, 32); ao.y = __shfl_xor(acc.y, 32);
  ao.z = __shfl_xor(acc.z, 32); ao.w = __shfl_xor(acc.w, 32);
  const float mm = fmaxf(m, mo);
  const float w0 = __expf(m - mm), w1 = __expf(mo - mm);
  const float lm = l * w0 + lo * w1;
  f4_ am = acc * w0 + ao * w1;

  if (half == 0) {
    *(f4_*)&sacc[w][l32 * 4] = am;
    if (l32 == 0) { sm[w] = mm; sl[w] = lm; }
  }
  __syncthreads();

  if (threadIdx.x < 32) {
    const int t = threadIdx.x;
    float mg = NEG_BIG_;
#pragma unroll
    for (int u = 0; u < 4; ++u)
      if (sl[u] > 0.f) mg = fmaxf(mg, sm[u]);
    float ls = 0.f;
    f4_ o = (f4_)0.f;
#pragma unroll
    for (int u = 0; u < 4; ++u)
      if (sl[u] > 0.f) {
        const float wu = __expf(sm[u] - mg);
        ls += sl[u] * wu;
        o  += wu * ld4(&sacc[u][t * 4]);
      }
    float* pb = part + (size_t)bid * PSTR_;
    *(f4_*)(pb + 4 + t * 4) = o;
    if (t == 0) { pb[0] = (ls > 0.f) ? mg : NEG_BIG_; pb[1] = ls; }
  }
}

// Merge the 4 split partials per (b,h) into attn output [b][h*128+d].
__global__ __launch_bounds__(128) void attn_combine(
    const float* __restrict__ part, float* __restrict__ attnout)
{
  const int pair = blockIdx.x;
  const int d    = threadIdx.x;
  const float* pb = part + (size_t)pair * NSPLIT_ * PSTR_;

  float mg = NEG_BIG_;
#pragma unroll
  for (int u = 0; u < NSPLIT_; ++u) {
    const float lu = pb[u * PSTR_ + 1];
    if (lu > 0.f) mg = fmaxf(mg, pb[u * PSTR_]);
  }
  float ls = 0.f, o = 0.f;
#pragma unroll
  for (int u = 0; u < NSPLIT_; ++u) {
    const float lu = pb[u * PSTR_ + 1];
    if (lu > 0.f) {
      const float wu = __expf(pb[u * PSTR_] - mg);
      ls += lu * wu;
      o  += wu * pb[u * PSTR_ + 4 + d];
    }
  }
  attnout[pair * HD_ + d] = o / ls;
}

extern "C" void kernel_launch(void* const* d_in, const int* in_sizes, int n_in,
                              void* d_out, int out_size, void* d_ws, size_t ws_size,
                              hipStream_t stream) {
  const float* x  = (const float*)d_in[0];
  const float* ck = (const float*)d_in[1];
  const float* cv = (const float*)d_in[2];
  const float* wq = (const float*)d_in[3];
  const float* wk = (const float*)d_in[4];
  const float* wv = (const float*)d_in[5];
  const float* wo = (const float*)d_in[6];
  const int* pos  = (const int*)d_in[7];
  float* out = (float*)d_out;
  float* ws  = (float*)d_ws;

  float* qkv     = ws;                                   // 3*8*4096 floats
  float* part    = ws + 3 * B_ * HID_;                   // 1024 * 132 floats
  float* attnout = part + NPAIR_ * NSPLIT_ * PSTR_;      // 8*4096 floats

  gemv8<<<3 * 512, 64, 0, stream>>>(wq, wk, wv, x, qkv, 512);
  attn_partial<<<NPAIR_ * NSPLIT_, 256, 0, stream>>>(qkv, ck, cv, pos, part);
  attn_combine<<<NPAIR_, 128, 0, stream>>>(part, attnout);
  gemv8<<<512, 64, 0, stream>>>(wo, wo, wo, attnout, out, 512);
}